// Round 1
// baseline (418.980 us; speedup 1.0000x reference)
//
#include <hip/hip_runtime.h>

namespace {

constexpr int W_RES = 320, H_RES = 240, BS = 4, VD = 128, NS = 256;
constexpr float DENS_SCALE = 100.0f / 256.0f;
constexpr long long VOX = (long long)VD * VD * VD;  // 2,097,152

// Transpose (B,4,D,H,W) fp32 -> (B,D,H,W) float4 (channel-interleaved).
__global__ void transpose_k(const float* __restrict__ vol, float4* __restrict__ out) {
    long long tid = (long long)blockIdx.x * blockDim.x + threadIdx.x;
    if (tid >= (long long)BS * VOX) return;
    int b = (int)(tid / VOX);
    long long r = tid - (long long)b * VOX;
    const float* vb = vol + (long long)b * 4 * VOX;
    float4 v;
    v.x = vb[r];            // color R
    v.y = vb[r + VOX];      // color G
    v.z = vb[r + 2 * VOX];  // color B
    v.w = vb[r + 3 * VOX];  // density
    out[tid] = v;
}

template <bool USE4>
__global__ void __launch_bounds__(256) raycast_k(const float* __restrict__ vol,
                                                 const float4* __restrict__ vol4,
                                                 const float* __restrict__ tfm,
                                                 float* __restrict__ out) {
    int tid = blockIdx.x * blockDim.x + threadIdx.x;
    constexpr int NPIX = W_RES * H_RES;
    if (tid >= BS * NPIX) return;
    int x = tid % W_RES;
    int y = (tid / W_RES) % H_RES;
    int b = tid / NPIX;

    float X = -1.0f + 2.0f * x / (float)(W_RES - 1);
    float Y = -1.0f + 2.0f * y / (float)(H_RES - 1);
    const float dZ = 2.0f / (float)(NS - 1);

    const float* M = tfm + b * 16;
    // tc = M @ [X, Y, Z, 1];   tc_i = base_i + M[i][2] * Z
    float bx = M[0] * X + M[1] * Y + M[3];
    float by = M[4] * X + M[5] * Y + M[7];
    float bz = M[8] * X + M[9] * Y + M[11];
    float bw = M[12] * X + M[13] * Y + M[15];
    float m02 = M[2], m12 = M[6], m22 = M[10], m32 = M[14];

    const float* vb = vol + (long long)b * 4 * VOX;
    const float4* vb4 = vol4 + (long long)b * VOX;

    float T = 1.0f, wsum = 0.0f;
    float aR = 0.0f, aG = 0.0f, aB = 0.0f;

    for (int s = 0; s < NS; ++s) {
        float Z = fmaf((float)s, dZ, -1.0f);
        float tcx = fmaf(m02, Z, bx);
        float tcy = fmaf(m12, Z, by);
        float tcz = fmaf(m22, Z, bz);
        float tcw = fmaf(m32, Z, bw);
        float invw = 1.0f / tcw;  // == 1 for these transforms, kept general
        float gx = tcx * invw, gy = tcy * invw, gz = tcz * invw;

        // ix = ((gx+1)*128 - 1) * 0.5 == gx*64 + 63.5
        float ix = fmaf(gx, 64.0f, 63.5f);
        float iy = fmaf(gy, 64.0f, 63.5f);
        float iz = fmaf(gz, 64.0f, 63.5f);
        float fx0 = floorf(ix), fy0 = floorf(iy), fz0 = floorf(iz);
        float fx = ix - fx0, fy = iy - fy0, fz = iz - fz0;
        int x0 = (int)fx0, y0 = (int)fy0, z0 = (int)fz0;

        float wxa0 = 1.0f - fx, wxa1 = fx;
        float wya0 = 1.0f - fy, wya1 = fy;
        float wza0 = 1.0f - fz, wza1 = fz;

        float accx = 0.0f, accy = 0.0f, accz = 0.0f, accw = 0.0f;

        #pragma unroll
        for (int cz = 0; cz < 2; ++cz) {
            int zz = z0 + cz;
            if ((unsigned)zz >= (unsigned)VD) continue;
            float wz1 = cz ? wza1 : wza0;
            #pragma unroll
            for (int cy = 0; cy < 2; ++cy) {
                int yy = y0 + cy;
                if ((unsigned)yy >= (unsigned)VD) continue;
                float wzy = wz1 * (cy ? wya1 : wya0);
                #pragma unroll
                for (int cx = 0; cx < 2; ++cx) {
                    int xx = x0 + cx;
                    if ((unsigned)xx >= (unsigned)VD) continue;
                    float w = wzy * (cx ? wxa1 : wxa0);
                    long long idx = ((long long)zz * VD + yy) * VD + xx;
                    if (USE4) {
                        float4 p = vb4[idx];
                        accx = fmaf(w, p.x, accx);
                        accy = fmaf(w, p.y, accy);
                        accz = fmaf(w, p.z, accz);
                        accw = fmaf(w, p.w, accw);
                    } else {
                        accx = fmaf(w, vb[idx], accx);
                        accy = fmaf(w, vb[idx + VOX], accy);
                        accz = fmaf(w, vb[idx + 2 * VOX], accz);
                        accw = fmaf(w, vb[idx + 3 * VOX], accw);
                    }
                }
            }
        }

        float dsv = accw * DENS_SCALE;
        T *= (1.0f - dsv);           // transmission_s = prod_{k<=s}(1-ds_k)
        float wgt = dsv * T;         // weight_s = ds_s * transmission_s
        wsum += wgt;
        aR = fmaf(wgt, accx, aR);
        aG = fmaf(wgt, accy, aG);
        aB = fmaf(wgt, accz, aB);

        if (T < 1e-6f) break;        // remaining contributions bounded by 1e-6
    }

    float scale = (1.0f - T) / (wsum + 1e-6f);  // alpha / (w_sum + 1e-6)
    int po = y * W_RES + x;
    float* ob = out + (long long)b * 3 * NPIX;
    ob[po] = aR * scale;
    ob[po + NPIX] = aG * scale;
    ob[po + 2 * NPIX] = aB * scale;
}

}  // namespace

extern "C" void kernel_launch(void* const* d_in, const int* in_sizes, int n_in,
                              void* d_out, int out_size, void* d_ws, size_t ws_size,
                              hipStream_t stream) {
    const float* vol = (const float*)d_in[0];  // (4,4,128,128,128) fp32
    const float* tfm = (const float*)d_in[1];  // (4,4,4) fp32
    float* out = (float*)d_out;                // (4,3,240,320) fp32

    const size_t need = (size_t)BS * VOX * sizeof(float4);  // 134,217,728 B
    const bool use4 = (d_ws != nullptr) && (ws_size >= need);

    const int total = BS * W_RES * H_RES;  // 307,200
    const int block = 256;

    if (use4) {
        float4* v4 = (float4*)d_ws;
        const long long nvox = (long long)BS * VOX;  // 8,388,608
        transpose_k<<<(int)((nvox + 255) / 256), 256, 0, stream>>>(vol, v4);
        raycast_k<true><<<(total + block - 1) / block, block, 0, stream>>>(vol, v4, tfm, out);
    } else {
        raycast_k<false><<<(total + block - 1) / block, block, 0, stream>>>(vol, nullptr, tfm, out);
    }
}

// Round 2
// 216.090 us; speedup vs baseline: 1.9389x; 1.9389x over previous
//
#include <hip/hip_runtime.h>

namespace {

constexpr int W_RES = 320, H_RES = 240, BS = 4, VD = 128, NS = 256;
constexpr float DENS_SCALE = 100.0f / 256.0f;
constexpr long long VOX = (long long)VD * VD * VD;  // 2,097,152

// Transpose (B,4,D,H,W) fp32 -> (B,D,H,W) float4 (channel-interleaved).
__global__ void transpose_k(const float* __restrict__ vol, float4* __restrict__ out) {
    long long tid = (long long)blockIdx.x * blockDim.x + threadIdx.x;
    if (tid >= (long long)BS * VOX) return;
    int b = (int)(tid / VOX);
    long long r = tid - (long long)b * VOX;
    const float* vb = vol + (long long)b * 4 * VOX;
    float4 v;
    v.x = vb[r];
    v.y = vb[r + VOX];
    v.z = vb[r + 2 * VOX];
    v.w = vb[r + 3 * VOX];
    out[tid] = v;
}

struct Stage {
    float4 p[8];
    float w[8];
};

__device__ __forceinline__ void stage_sample(const float4* __restrict__ vb4,
                                             float ix, float iy, float iz, Stage& st) {
    float fx0 = floorf(ix), fy0 = floorf(iy), fz0 = floorf(iz);
    float fx = ix - fx0, fy = iy - fy0, fz = iz - fz0;
    int x0 = (int)fx0, y0 = (int)fy0, z0 = (int)fz0;

    // validity folded into per-axis weights (branch-free)
    float mx0 = ((unsigned)x0 < 128u) ? 1.0f : 0.0f;
    float mx1 = ((unsigned)(x0 + 1) < 128u) ? 1.0f : 0.0f;
    float my0 = ((unsigned)y0 < 128u) ? 1.0f : 0.0f;
    float my1 = ((unsigned)(y0 + 1) < 128u) ? 1.0f : 0.0f;
    float mz0 = ((unsigned)z0 < 128u) ? 1.0f : 0.0f;
    float mz1 = ((unsigned)(z0 + 1) < 128u) ? 1.0f : 0.0f;
    float wx0 = (1.0f - fx) * mx0, wx1 = fx * mx1;
    float wy0 = (1.0f - fy) * my0, wy1 = fy * my1;
    float wz0 = (1.0f - fz) * mz0, wz1 = fz * mz1;

    int xc0 = min(max(x0, 0), 127), xc1 = min(max(x0 + 1, 0), 127);
    int yc0 = min(max(y0, 0), 127), yc1 = min(max(y0 + 1, 0), 127);
    int zc0 = min(max(z0, 0), 127), zc1 = min(max(z0 + 1, 0), 127);

    int r00 = (zc0 * VD + yc0) * VD, r01 = (zc0 * VD + yc1) * VD;
    int r10 = (zc1 * VD + yc0) * VD, r11 = (zc1 * VD + yc1) * VD;

    st.p[0] = vb4[r00 + xc0];
    st.p[1] = vb4[r00 + xc1];
    st.p[2] = vb4[r01 + xc0];
    st.p[3] = vb4[r01 + xc1];
    st.p[4] = vb4[r10 + xc0];
    st.p[5] = vb4[r10 + xc1];
    st.p[6] = vb4[r11 + xc0];
    st.p[7] = vb4[r11 + xc1];

    st.w[0] = wz0 * wy0 * wx0;
    st.w[1] = wz0 * wy0 * wx1;
    st.w[2] = wz0 * wy1 * wx0;
    st.w[3] = wz0 * wy1 * wx1;
    st.w[4] = wz1 * wy0 * wx0;
    st.w[5] = wz1 * wy0 * wx1;
    st.w[6] = wz1 * wy1 * wx0;
    st.w[7] = wz1 * wy1 * wx1;
}

__device__ __forceinline__ void consume(const Stage& st, float& T, float& wsum,
                                        float& aR, float& aG, float& aB) {
    float ax0 = 0, ay0 = 0, az0 = 0, aw0 = 0;
    float ax1 = 0, ay1 = 0, az1 = 0, aw1 = 0;
#pragma unroll
    for (int i = 0; i < 8; i += 2) {
        ax0 = fmaf(st.w[i], st.p[i].x, ax0);
        ay0 = fmaf(st.w[i], st.p[i].y, ay0);
        az0 = fmaf(st.w[i], st.p[i].z, az0);
        aw0 = fmaf(st.w[i], st.p[i].w, aw0);
        ax1 = fmaf(st.w[i + 1], st.p[i + 1].x, ax1);
        ay1 = fmaf(st.w[i + 1], st.p[i + 1].y, ay1);
        az1 = fmaf(st.w[i + 1], st.p[i + 1].z, az1);
        aw1 = fmaf(st.w[i + 1], st.p[i + 1].w, aw1);
    }
    float dsv = (aw0 + aw1) * DENS_SCALE;
    T *= (1.0f - dsv);
    float wgt = dsv * T;
    wsum += wgt;
    aR = fmaf(wgt, ax0 + ax1, aR);
    aG = fmaf(wgt, ay0 + ay1, aG);
    aB = fmaf(wgt, az0 + az1, aB);
}

__global__ void __launch_bounds__(64) raycast_k(const float4* __restrict__ vol4,
                                                const float* __restrict__ tfm,
                                                float* __restrict__ out) {
    constexpr int NPIX = W_RES * H_RES;
    int lane = threadIdx.x;
    int x = blockIdx.x * 8 + (lane & 7);
    int y = blockIdx.y * 8 + (lane >> 3);
    int b = blockIdx.z;

    float X = -1.0f + 2.0f * x / (float)(W_RES - 1);
    float Y = -1.0f + 2.0f * y / (float)(H_RES - 1);
    const float dZ = 2.0f / (float)(NS - 1);

    const float* M = tfm + b * 16;
    float bx = M[0] * X + M[1] * Y + M[3];
    float by = M[4] * X + M[5] * Y + M[7];
    float bz = M[8] * X + M[9] * Y + M[11];
    float bw = M[12] * X + M[13] * Y + M[15];
    float m02 = M[2], m12 = M[6], m22 = M[10], m32 = M[14];

    const float4* vb4 = vol4 + (long long)b * VOX;

    // Ray-box clip (valid only when the w row is trivial; true for these tfms,
    // but guarded for generality).
    bool w1 = (fabsf(bw - 1.0f) < 1e-6f) && (fabsf(m32) < 1e-6f);
    float lo = 0.0f, hi = (float)(NS - 1);
    if (w1) {
        const float LIM = 1.0078125f + 1e-5f;  // ix in [-1,128) <=> |gx| <= 64.5/64
        auto clipAxis = [&](float bb, float mm) {
            float A = bb - mm;       // g(s) = A + B*s
            float B = mm * dZ;
            if (fabsf(B) < 1e-9f) {
                if (fabsf(A) > LIM) { lo = 1.0f; hi = 0.0f; }
            } else {
                float s1 = (-LIM - A) / B, s2 = (LIM - A) / B;
                lo = fmaxf(lo, fminf(s1, s2));
                hi = fminf(hi, fmaxf(s1, s2));
            }
        };
        clipAxis(bx, m02);
        clipAxis(by, m12);
        clipAxis(bz, m22);
    }
    int s_start = max(0, (int)ceilf(lo - 1e-3f));
    int s_end = min(NS - 1, (int)floorf(hi + 1e-3f));

    auto coords = [&](int s, float& ix, float& iy, float& iz) {
        float Z = fmaf((float)s, dZ, -1.0f);
        float gx = fmaf(m02, Z, bx);
        float gy = fmaf(m12, Z, by);
        float gz = fmaf(m22, Z, bz);
        if (!w1) {
            float iw = 1.0f / fmaf(m32, Z, bw);
            gx *= iw; gy *= iw; gz *= iw;
        }
        ix = fmaf(gx, 64.0f, 63.5f);
        iy = fmaf(gy, 64.0f, 63.5f);
        iz = fmaf(gz, 64.0f, 63.5f);
    };

    float T = 1.0f, wsum = 0.0f, aR = 0.0f, aG = 0.0f, aB = 0.0f;

    if (s_start <= s_end) {
        Stage A, B;
        float ix, iy, iz;
        int s = s_start;
        coords(s, ix, iy, iz);
        stage_sample(vb4, ix, iy, iz, A);
        while (true) {
            // even: prefetch into B, consume A
            bool more = (s + 1 <= s_end);
            if (more) {
                coords(s + 1, ix, iy, iz);
                stage_sample(vb4, ix, iy, iz, B);
            }
            consume(A, T, wsum, aR, aG, aB);
            if (T < 1e-6f || !more) break;
            ++s;
            // odd: prefetch into A, consume B
            more = (s + 1 <= s_end);
            if (more) {
                coords(s + 1, ix, iy, iz);
                stage_sample(vb4, ix, iy, iz, A);
            }
            consume(B, T, wsum, aR, aG, aB);
            if (T < 1e-6f || !more) break;
            ++s;
        }
    }

    float scale = (1.0f - T) / (wsum + 1e-6f);
    int po = y * W_RES + x;
    float* ob = out + (long long)b * 3 * NPIX;
    ob[po] = aR * scale;
    ob[po + NPIX] = aG * scale;
    ob[po + 2 * NPIX] = aB * scale;
}

}  // namespace

extern "C" void kernel_launch(void* const* d_in, const int* in_sizes, int n_in,
                              void* d_out, int out_size, void* d_ws, size_t ws_size,
                              hipStream_t stream) {
    const float* vol = (const float*)d_in[0];  // (4,4,128,128,128) fp32
    const float* tfm = (const float*)d_in[1];  // (4,4,4) fp32
    float* out = (float*)d_out;                // (4,3,240,320) fp32

    const size_t need = (size_t)BS * VOX * sizeof(float4);  // 134 MB
    float4* v4 = (float4*)d_ws;
    (void)ws_size; (void)need;

    const long long nvox = (long long)BS * VOX;
    transpose_k<<<(int)((nvox + 255) / 256), 256, 0, stream>>>(vol, v4);

    dim3 grid(W_RES / 8, H_RES / 8, BS);  // 40 x 30 x 4, 8x8 pixel tiles
    raycast_k<<<grid, 64, 0, stream>>>(v4, tfm, out);
}

// Round 3
// 185.705 us; speedup vs baseline: 2.2562x; 1.1636x over previous
//
#include <hip/hip_runtime.h>

namespace {

constexpr int W_RES = 320, H_RES = 240, BS = 4, VD = 128, NS = 256;
constexpr float DENS_SCALE = 100.0f / 256.0f;
constexpr float TAU = 5e-4f;  // early-exit transmittance; adds <=~1e-3 abs error
constexpr long long VOX = (long long)VD * VD * VD;  // 2,097,152

// Transpose (B,4,D,H,W) fp32 -> (B,D,H,W) float4 (channel-interleaved).
__global__ void transpose_k(const float* __restrict__ vol, float4* __restrict__ out) {
    long long tid = (long long)blockIdx.x * blockDim.x + threadIdx.x;
    if (tid >= (long long)BS * VOX) return;
    int b = (int)(tid / VOX);
    long long r = tid - (long long)b * VOX;
    const float* vb = vol + (long long)b * 4 * VOX;
    float4 v;
    v.x = vb[r];
    v.y = vb[r + VOX];
    v.z = vb[r + 2 * VOX];
    v.w = vb[r + 3 * VOX];
    out[tid] = v;
}

struct Stage {
    float4 p[8];
    float w[8];
};

__device__ __forceinline__ void stage_sample(const float4* __restrict__ vb4,
                                             float ix, float iy, float iz, Stage& st) {
    float fx0 = floorf(ix), fy0 = floorf(iy), fz0 = floorf(iz);
    float fx = ix - fx0, fy = iy - fy0, fz = iz - fz0;
    int x0 = (int)fx0, y0 = (int)fy0, z0 = (int)fz0;

    float mx0 = ((unsigned)x0 < 128u) ? 1.0f : 0.0f;
    float mx1 = ((unsigned)(x0 + 1) < 128u) ? 1.0f : 0.0f;
    float my0 = ((unsigned)y0 < 128u) ? 1.0f : 0.0f;
    float my1 = ((unsigned)(y0 + 1) < 128u) ? 1.0f : 0.0f;
    float mz0 = ((unsigned)z0 < 128u) ? 1.0f : 0.0f;
    float mz1 = ((unsigned)(z0 + 1) < 128u) ? 1.0f : 0.0f;
    float wx0 = (1.0f - fx) * mx0, wx1 = fx * mx1;
    float wy0 = (1.0f - fy) * my0, wy1 = fy * my1;
    float wz0 = (1.0f - fz) * mz0, wz1 = fz * mz1;

    int xc0 = min(max(x0, 0), 127), xc1 = min(max(x0 + 1, 0), 127);
    int yc0 = min(max(y0, 0), 127), yc1 = min(max(y0 + 1, 0), 127);
    int zc0 = min(max(z0, 0), 127), zc1 = min(max(z0 + 1, 0), 127);

    int r00 = (zc0 * VD + yc0) * VD, r01 = (zc0 * VD + yc1) * VD;
    int r10 = (zc1 * VD + yc0) * VD, r11 = (zc1 * VD + yc1) * VD;

    st.p[0] = vb4[r00 + xc0];
    st.p[1] = vb4[r00 + xc1];
    st.p[2] = vb4[r01 + xc0];
    st.p[3] = vb4[r01 + xc1];
    st.p[4] = vb4[r10 + xc0];
    st.p[5] = vb4[r10 + xc1];
    st.p[6] = vb4[r11 + xc0];
    st.p[7] = vb4[r11 + xc1];

    st.w[0] = wz0 * wy0 * wx0;
    st.w[1] = wz0 * wy0 * wx1;
    st.w[2] = wz0 * wy1 * wx0;
    st.w[3] = wz0 * wy1 * wx1;
    st.w[4] = wz1 * wy0 * wx0;
    st.w[5] = wz1 * wy0 * wx1;
    st.w[6] = wz1 * wy1 * wx0;
    st.w[7] = wz1 * wy1 * wx1;
}

__device__ __forceinline__ void consume(const Stage& st, float& T, float& wsum,
                                        float& aR, float& aG, float& aB) {
    float ax0 = 0, ay0 = 0, az0 = 0, aw0 = 0;
    float ax1 = 0, ay1 = 0, az1 = 0, aw1 = 0;
#pragma unroll
    for (int i = 0; i < 8; i += 2) {
        ax0 = fmaf(st.w[i], st.p[i].x, ax0);
        ay0 = fmaf(st.w[i], st.p[i].y, ay0);
        az0 = fmaf(st.w[i], st.p[i].z, az0);
        aw0 = fmaf(st.w[i], st.p[i].w, aw0);
        ax1 = fmaf(st.w[i + 1], st.p[i + 1].x, ax1);
        ay1 = fmaf(st.w[i + 1], st.p[i + 1].y, ay1);
        az1 = fmaf(st.w[i + 1], st.p[i + 1].z, az1);
        aw1 = fmaf(st.w[i + 1], st.p[i + 1].w, aw1);
    }
    float dsv = (aw0 + aw1) * DENS_SCALE;
    T *= (1.0f - dsv);
    float wgt = dsv * T;
    wsum += wgt;
    aR = fmaf(wgt, ax0 + ax1, aR);
    aG = fmaf(wgt, ay0 + ay1, aG);
    aB = fmaf(wgt, az0 + az1, aB);
}

__global__ void __launch_bounds__(64) raycast_k(const float4* __restrict__ vol4,
                                                const float* __restrict__ tfm,
                                                float* __restrict__ out) {
    constexpr int NPIX = W_RES * H_RES;
    int lane = threadIdx.x;
    int x = blockIdx.x * 16 + (lane & 15);  // 16x4 pixel tile per wave
    int y = blockIdx.y * 4 + (lane >> 4);
    int b = blockIdx.z;

    float X = -1.0f + 2.0f * x / (float)(W_RES - 1);
    float Y = -1.0f + 2.0f * y / (float)(H_RES - 1);
    const float dZ = 2.0f / (float)(NS - 1);

    const float* M = tfm + b * 16;
    float bx = M[0] * X + M[1] * Y + M[3];
    float by = M[4] * X + M[5] * Y + M[7];
    float bz = M[8] * X + M[9] * Y + M[11];
    float bw = M[12] * X + M[13] * Y + M[15];
    float m02 = M[2], m12 = M[6], m22 = M[10], m32 = M[14];

    const float4* vb4 = vol4 + (long long)b * VOX;

    // Ray-box clip (exact when the w row is trivial; guarded for generality).
    bool w1 = (fabsf(bw - 1.0f) < 1e-6f) && (fabsf(m32) < 1e-6f);
    float lo = 0.0f, hi = (float)(NS - 1);
    if (w1) {
        const float LIM = 1.0078125f + 1e-5f;  // some corner valid <=> |g| < 64.5/64
        auto clipAxis = [&](float bb, float mm) {
            float A = bb - mm;  // g(s) = A + B*s
            float B = mm * dZ;
            if (fabsf(B) < 1e-9f) {
                if (fabsf(A) > LIM) { lo = 1.0f; hi = 0.0f; }
            } else {
                float s1 = (-LIM - A) / B, s2 = (LIM - A) / B;
                lo = fmaxf(lo, fminf(s1, s2));
                hi = fminf(hi, fmaxf(s1, s2));
            }
        };
        clipAxis(bx, m02);
        clipAxis(by, m12);
        clipAxis(bz, m22);
    }
    int s_start = max(0, (int)ceilf(lo - 1e-3f));
    int s_end = min(NS - 1, (int)floorf(hi + 1e-3f));

    // wave-common loop bounds
    int wsv = s_start, wev = s_end;
#pragma unroll
    for (int off = 1; off < 64; off <<= 1) {
        wsv = min(wsv, __shfl_xor(wsv, off));
        wev = max(wev, __shfl_xor(wev, off));
    }

    auto coords = [&](int s, float& ix, float& iy, float& iz) {
        float Z = fmaf((float)s, dZ, -1.0f);
        float gx = fmaf(m02, Z, bx);
        float gy = fmaf(m12, Z, by);
        float gz = fmaf(m22, Z, bz);
        if (!w1) {
            float iw = 1.0f / fmaf(m32, Z, bw);
            gx *= iw; gy *= iw; gz *= iw;
        }
        ix = fmaf(gx, 64.0f, 63.5f);
        iy = fmaf(gy, 64.0f, 63.5f);
        iz = fmaf(gz, 64.0f, 63.5f);
    };

    float T = 1.0f, wsum = 0.0f, aR = 0.0f, aG = 0.0f, aB = 0.0f;
    Stage A, B;

    for (int s = wsv; s <= wev; s += 2) {
        // Issue both samples' 16 gathers before any consume (true depth-2 MLP).
        bool g0 = (s >= s_start) & (s <= s_end) & (T >= TAU);
        if (g0) {
            float ix, iy, iz;
            coords(s, ix, iy, iz);
            stage_sample(vb4, ix, iy, iz, A);
        }
        bool g1 = (s + 1 >= s_start) & (s + 1 <= s_end) & (T >= TAU);
        if (g1) {
            float ix, iy, iz;
            coords(s + 1, ix, iy, iz);
            stage_sample(vb4, ix, iy, iz, B);
        }
        __builtin_amdgcn_sched_barrier(0);  // don't sink loads past here
        if (g0) consume(A, T, wsum, aR, aG, aB);
        if (g1 & (T >= TAU)) consume(B, T, wsum, aR, aG, aB);
        if (!__any((T >= TAU) & (s + 2 <= s_end))) break;
    }

    float scale = (1.0f - T) / (wsum + 1e-6f);
    int po = y * W_RES + x;
    float* ob = out + (long long)b * 3 * NPIX;
    ob[po] = aR * scale;
    ob[po + NPIX] = aG * scale;
    ob[po + 2 * NPIX] = aB * scale;
}

}  // namespace

extern "C" void kernel_launch(void* const* d_in, const int* in_sizes, int n_in,
                              void* d_out, int out_size, void* d_ws, size_t ws_size,
                              hipStream_t stream) {
    const float* vol = (const float*)d_in[0];  // (4,4,128,128,128) fp32
    const float* tfm = (const float*)d_in[1];  // (4,4,4) fp32
    float* out = (float*)d_out;                // (4,3,240,320) fp32

    float4* v4 = (float4*)d_ws;
    (void)ws_size; (void)in_sizes; (void)n_in; (void)out_size;

    const long long nvox = (long long)BS * VOX;
    transpose_k<<<(int)((nvox + 255) / 256), 256, 0, stream>>>(vol, v4);

    dim3 grid(W_RES / 16, H_RES / 4, BS);  // 20 x 60 x 4 = 4800 single-wave blocks
    raycast_k<<<grid, 64, 0, stream>>>(v4, tfm, out);
}

// Round 4
// 172.966 us; speedup vs baseline: 2.4223x; 1.0737x over previous
//
#include <hip/hip_runtime.h>
#include <hip/hip_fp16.h>

namespace {

constexpr int W_RES = 320, H_RES = 240, BS = 4, VD = 128, NS = 256;
constexpr float DENS_SCALE = 100.0f / 256.0f;
constexpr float TAU = 5e-4f;  // early-exit transmittance; adds <=~1e-3 abs error
constexpr long long VOX = (long long)VD * VD * VD;  // 2,097,152

__device__ __forceinline__ unsigned h2u(__half2 h) {
    unsigned u; __builtin_memcpy(&u, &h, 4); return u;
}
__device__ __forceinline__ __half2 u2h(unsigned u) {
    __half2 h; __builtin_memcpy(&h, &u, 4); return h;
}

// Transpose (B,4,D,H,W) fp32 -> (B,D,H,W) packed fp16x4 {rg, bd}, 8 B/voxel.
// Each thread converts 2 voxels (reads 4x float2, writes 1x uint4).
__global__ void transpose_k(const float* __restrict__ vol, uint4* __restrict__ out) {
    long long tid = (long long)blockIdx.x * blockDim.x + threadIdx.x;
    const long long npair = (long long)BS * VOX / 2;
    if (tid >= npair) return;
    int b = (int)(tid / (VOX / 2));
    long long r2 = (tid - (long long)b * (VOX / 2)) * 2;
    const float* vb = vol + (long long)b * 4 * VOX + r2;
    float2 R = *(const float2*)(vb);
    float2 G = *(const float2*)(vb + VOX);
    float2 Bc = *(const float2*)(vb + 2 * VOX);
    float2 Dn = *(const float2*)(vb + 3 * VOX);
    uint4 o;
    o.x = h2u(__floats2half2_rn(R.x, G.x));
    o.y = h2u(__floats2half2_rn(Bc.x, Dn.x));
    o.z = h2u(__floats2half2_rn(R.y, G.y));
    o.w = h2u(__floats2half2_rn(Bc.y, Dn.y));
    out[tid] = o;
}

struct Stage {
    uint2 p[8];   // packed fp16x4 per corner
    float w[8];
};

struct Coord {
    int x0, y0, z0;
    float fx, fy, fz;
    bool fast;  // all 8 corners in-bounds
};

__device__ __forceinline__ Coord make_coord(float ix, float iy, float iz) {
    Coord c;
    float fx0 = floorf(ix), fy0 = floorf(iy), fz0 = floorf(iz);
    c.fx = ix - fx0; c.fy = iy - fy0; c.fz = iz - fz0;
    c.x0 = (int)fx0; c.y0 = (int)fy0; c.z0 = (int)fz0;
    c.fast = ((unsigned)c.x0 < 127u) & ((unsigned)c.y0 < 127u) & ((unsigned)c.z0 < 127u);
    return c;
}

__device__ __forceinline__ void weights_plain(const Coord& c, Stage& st) {
    float wx0 = 1.0f - c.fx, wx1 = c.fx;
    float wy0 = 1.0f - c.fy, wy1 = c.fy;
    float wz0 = 1.0f - c.fz, wz1 = c.fz;
    float w00 = wz0 * wy0, w01 = wz0 * wy1, w10 = wz1 * wy0, w11 = wz1 * wy1;
    st.w[0] = w00 * wx0; st.w[1] = w00 * wx1;
    st.w[2] = w01 * wx0; st.w[3] = w01 * wx1;
    st.w[4] = w10 * wx0; st.w[5] = w10 * wx1;
    st.w[6] = w11 * wx0; st.w[7] = w11 * wx1;
}

// All corners in-bounds: 2 base addresses + immediate offsets.
__device__ __forceinline__ void stage_fast(const uint2* __restrict__ vb,
                                           const Coord& c, Stage& st) {
    const uint2* r0 = vb + ((c.z0 * VD + c.y0) * VD + c.x0);
    const uint2* r1 = r0 + VD * VD;
    st.p[0] = r0[0];      st.p[1] = r0[1];
    st.p[2] = r0[VD];     st.p[3] = r0[VD + 1];
    st.p[4] = r1[0];      st.p[5] = r1[1];
    st.p[6] = r1[VD];     st.p[7] = r1[VD + 1];
    weights_plain(c, st);
}

__device__ __forceinline__ void stage_safe(const uint2* __restrict__ vb,
                                           const Coord& c, Stage& st) {
    int x0 = c.x0, y0 = c.y0, z0 = c.z0;
    float mx0 = ((unsigned)x0 < 128u) ? 1.0f : 0.0f;
    float mx1 = ((unsigned)(x0 + 1) < 128u) ? 1.0f : 0.0f;
    float my0 = ((unsigned)y0 < 128u) ? 1.0f : 0.0f;
    float my1 = ((unsigned)(y0 + 1) < 128u) ? 1.0f : 0.0f;
    float mz0 = ((unsigned)z0 < 128u) ? 1.0f : 0.0f;
    float mz1 = ((unsigned)(z0 + 1) < 128u) ? 1.0f : 0.0f;
    float wx0 = (1.0f - c.fx) * mx0, wx1 = c.fx * mx1;
    float wy0 = (1.0f - c.fy) * my0, wy1 = c.fy * my1;
    float wz0 = (1.0f - c.fz) * mz0, wz1 = c.fz * mz1;

    int xc0 = min(max(x0, 0), 127), xc1 = min(max(x0 + 1, 0), 127);
    int yc0 = min(max(y0, 0), 127), yc1 = min(max(y0 + 1, 0), 127);
    int zc0 = min(max(z0, 0), 127), zc1 = min(max(z0 + 1, 0), 127);

    int r00 = (zc0 * VD + yc0) * VD, r01 = (zc0 * VD + yc1) * VD;
    int r10 = (zc1 * VD + yc0) * VD, r11 = (zc1 * VD + yc1) * VD;

    st.p[0] = vb[r00 + xc0]; st.p[1] = vb[r00 + xc1];
    st.p[2] = vb[r01 + xc0]; st.p[3] = vb[r01 + xc1];
    st.p[4] = vb[r10 + xc0]; st.p[5] = vb[r10 + xc1];
    st.p[6] = vb[r11 + xc0]; st.p[7] = vb[r11 + xc1];

    float w00 = wz0 * wy0, w01 = wz0 * wy1, w10 = wz1 * wy0, w11 = wz1 * wy1;
    st.w[0] = w00 * wx0; st.w[1] = w00 * wx1;
    st.w[2] = w01 * wx0; st.w[3] = w01 * wx1;
    st.w[4] = w10 * wx0; st.w[5] = w10 * wx1;
    st.w[6] = w11 * wx0; st.w[7] = w11 * wx1;
}

__device__ __forceinline__ void consume(const Stage& st, float& T, float& wsum,
                                        float& aR, float& aG, float& aB) {
    float ax0 = 0, ay0 = 0, az0 = 0, aw0 = 0;
    float ax1 = 0, ay1 = 0, az1 = 0, aw1 = 0;
#pragma unroll
    for (int i = 0; i < 8; i += 2) {
        __half2 rg0 = u2h(st.p[i].x), bd0 = u2h(st.p[i].y);
        __half2 rg1 = u2h(st.p[i + 1].x), bd1 = u2h(st.p[i + 1].y);
        ax0 = fmaf(st.w[i], __half2float(__low2half(rg0)), ax0);
        ay0 = fmaf(st.w[i], __half2float(__high2half(rg0)), ay0);
        az0 = fmaf(st.w[i], __half2float(__low2half(bd0)), az0);
        aw0 = fmaf(st.w[i], __half2float(__high2half(bd0)), aw0);
        ax1 = fmaf(st.w[i + 1], __half2float(__low2half(rg1)), ax1);
        ay1 = fmaf(st.w[i + 1], __half2float(__high2half(rg1)), ay1);
        az1 = fmaf(st.w[i + 1], __half2float(__low2half(bd1)), az1);
        aw1 = fmaf(st.w[i + 1], __half2float(__high2half(bd1)), aw1);
    }
    float dsv = (aw0 + aw1) * DENS_SCALE;
    T *= (1.0f - dsv);
    float wgt = dsv * T;
    wsum += wgt;
    aR = fmaf(wgt, ax0 + ax1, aR);
    aG = fmaf(wgt, ay0 + ay1, aG);
    aB = fmaf(wgt, az0 + az1, aB);
}

__global__ void __launch_bounds__(256) raycast_k(const uint2* __restrict__ vol8,
                                                 const float* __restrict__ tfm,
                                                 float* __restrict__ out) {
    constexpr int NPIX = W_RES * H_RES;
    int lane = threadIdx.x & 63;
    int wave = threadIdx.x >> 6;
    // block covers a 16x16 pixel region; each wave a 16x4 strip
    int bx = blockIdx.x % (W_RES / 16);
    int rest = blockIdx.x / (W_RES / 16);
    int by = rest % (H_RES / 16);
    int b = rest / (H_RES / 16);
    int x = bx * 16 + (lane & 15);
    int y = by * 16 + wave * 4 + (lane >> 4);

    float X = -1.0f + 2.0f * x / (float)(W_RES - 1);
    float Y = -1.0f + 2.0f * y / (float)(H_RES - 1);
    const float dZ = 2.0f / (float)(NS - 1);

    const float* M = tfm + b * 16;
    float bxc = M[0] * X + M[1] * Y + M[3];
    float byc = M[4] * X + M[5] * Y + M[7];
    float bzc = M[8] * X + M[9] * Y + M[11];
    float bwc = M[12] * X + M[13] * Y + M[15];
    float m02 = M[2], m12 = M[6], m22 = M[10], m32 = M[14];

    const uint2* vb = vol8 + (long long)b * VOX;

    // Ray-box clip (exact when the w row is trivial; guarded for generality).
    bool w1 = (fabsf(bwc - 1.0f) < 1e-6f) && (fabsf(m32) < 1e-6f);
    float lo = 0.0f, hi = (float)(NS - 1);
    if (w1) {
        const float LIM = 1.0078125f + 1e-5f;  // some corner valid <=> |g| < 64.5/64
        auto clipAxis = [&](float bb, float mm) {
            float A = bb - mm;  // g(s) = A + B*s
            float B = mm * dZ;
            if (fabsf(B) < 1e-9f) {
                if (fabsf(A) > LIM) { lo = 1.0f; hi = 0.0f; }
            } else {
                float s1 = (-LIM - A) / B, s2 = (LIM - A) / B;
                lo = fmaxf(lo, fminf(s1, s2));
                hi = fminf(hi, fmaxf(s1, s2));
            }
        };
        clipAxis(bxc, m02);
        clipAxis(byc, m12);
        clipAxis(bzc, m22);
    }
    int s_start = max(0, (int)ceilf(lo - 1e-3f));
    int s_end = min(NS - 1, (int)floorf(hi + 1e-3f));

    // wave-common loop bounds
    int wsv = s_start, wev = s_end;
#pragma unroll
    for (int off = 1; off < 64; off <<= 1) {
        wsv = min(wsv, __shfl_xor(wsv, off));
        wev = max(wev, __shfl_xor(wev, off));
    }

    auto coords = [&](int s, float& ix, float& iy, float& iz) {
        float Z = fmaf((float)s, dZ, -1.0f);
        float gx = fmaf(m02, Z, bxc);
        float gy = fmaf(m12, Z, byc);
        float gz = fmaf(m22, Z, bzc);
        if (!w1) {
            float iw = 1.0f / fmaf(m32, Z, bwc);
            gx *= iw; gy *= iw; gz *= iw;
        }
        ix = fmaf(gx, 64.0f, 63.5f);
        iy = fmaf(gy, 64.0f, 63.5f);
        iz = fmaf(gz, 64.0f, 63.5f);
    };

    float T = 1.0f, wsum = 0.0f, aR = 0.0f, aG = 0.0f, aB = 0.0f;
    Stage A, B, C;

    for (int s = wsv; s <= wev; s += 3) {
        bool alive = (T >= TAU);
        bool g0 = (s >= s_start) & (s <= s_end) & alive;
        bool g1 = (s + 1 >= s_start) & (s + 1 <= s_end) & alive;
        bool g2 = (s + 2 >= s_start) & (s + 2 <= s_end) & alive;
        Coord c0, c1, c2;
        float ix, iy, iz;
        if (g0) { coords(s, ix, iy, iz); c0 = make_coord(ix, iy, iz); }
        if (g1) { coords(s + 1, ix, iy, iz); c1 = make_coord(ix, iy, iz); }
        if (g2) { coords(s + 2, ix, iy, iz); c2 = make_coord(ix, iy, iz); }
        bool fastAll = __all((g0 ? c0.fast : true) & (g1 ? c1.fast : true) &
                             (g2 ? c2.fast : true));
        if (fastAll) {
            if (g0) stage_fast(vb, c0, A);
            if (g1) stage_fast(vb, c1, B);
            if (g2) stage_fast(vb, c2, C);
        } else {
            if (g0) stage_safe(vb, c0, A);
            if (g1) stage_safe(vb, c1, B);
            if (g2) stage_safe(vb, c2, C);
        }
        __builtin_amdgcn_sched_barrier(0);  // keep loads hoisted above consumes
        if (g0) consume(A, T, wsum, aR, aG, aB);
        if (g1 & (T >= TAU)) consume(B, T, wsum, aR, aG, aB);
        if (g2 & (T >= TAU)) consume(C, T, wsum, aR, aG, aB);
        if (!__any((T >= TAU) & (s + 3 <= s_end))) break;
    }

    float scale = (1.0f - T) / (wsum + 1e-6f);
    int po = y * W_RES + x;
    float* ob = out + (long long)b * 3 * NPIX;
    ob[po] = aR * scale;
    ob[po + NPIX] = aG * scale;
    ob[po + 2 * NPIX] = aB * scale;
}

}  // namespace

extern "C" void kernel_launch(void* const* d_in, const int* in_sizes, int n_in,
                              void* d_out, int out_size, void* d_ws, size_t ws_size,
                              hipStream_t stream) {
    const float* vol = (const float*)d_in[0];  // (4,4,128,128,128) fp32
    const float* tfm = (const float*)d_in[1];  // (4,4,4) fp32
    float* out = (float*)d_out;                // (4,3,240,320) fp32

    uint4* v16 = (uint4*)d_ws;  // fp16x4 packed volume, 67 MB
    (void)ws_size; (void)in_sizes; (void)n_in; (void)out_size;

    const long long npair = (long long)BS * VOX / 2;  // 4,194,304
    transpose_k<<<(int)((npair + 255) / 256), 256, 0, stream>>>(vol, v16);

    const int nblk = (W_RES / 16) * (H_RES / 16) * BS;  // 20*15*4 = 1200
    raycast_k<<<nblk, 256, 0, stream>>>((const uint2*)v16, tfm, out);
}